// Round 7
// baseline (156.659 us; speedup 1.0000x reference)
//
#include <hip/hip_runtime.h>

// Problem constants
#define B_  32
#define M_  64
#define K_  36
#define DS_ 512
#define DX_ 128
#define DQ_ 512
#define H_  256

#define TMA  16     // rows of s2 per GEMM block in kernA
#define DCH  128    // d-chunk (split-K factor 4)
#define KB   9      // k's per cvec block

// NB: param names must not collide with .x/.y/.z/.w member tokens!
#define FMA4(acc, sv, wv)              \
    acc.x = fmaf(sv, wv.x, acc.x);     \
    acc.y = fmaf(sv, wv.y, acc.y);     \
    acc.z = fmaf(sv, wv.z, acc.z);     \
    acc.w = fmaf(sv, wv.w, acc.w);

// ---------------------------------------------------------------------------
// Kernel A (grid = 1152, block = 256, no LDS):
//  blocks 0..127: cvec[b,k,h] = q[b]·w_q + x0[b,k]·w_x + score_b1
//    (cb = bid, b = cb>>2, k = (cb&3)*9 .. +8)  [launched first: long tail]
//  blocks 128..1151: g = bid-128, tile = g&127, mc = g>>7 (mat = mc&1,
//    dq = mc>>1). All 8 partial-blocks of a tile share bid%8 == tile%8
//    (same XCD -> atomics stay in one L2).
//    Wave w owns rows 4w..4w+3 (scalar s2 loads); lane owns h-quad 4*lane.
//    atomicAdd partial GEMM into (mat?ph1:pre_s).
// ---------------------------------------------------------------------------
__global__ __launch_bounds__(256) void kernA(
    const float* __restrict__ s2,        // (2048,512)
    const float* __restrict__ score_w1,  // (1152,256)
    const float* __restrict__ h_w1,      // (512,256)
    const float* __restrict__ q,         // (B,512)
    const float* __restrict__ score_b1,  // (256)
    const float* __restrict__ x0,        // (B*K,128)
    float* __restrict__ pre_s,           // (2048,256)  zero-init
    float* __restrict__ ph1,             // (2048,256)  zero-init
    float* __restrict__ cvec)            // (B*K,256)
{
    const int t   = threadIdx.x;
    const int bid = blockIdx.x;

    if (bid < 128) {                     // ---- cvec blocks ----
        const int cb = bid;
        const int b  = cb >> 2;
        const int kq = cb & 3;
        // q . w_q  (q via block-uniform scalar loads)
        const float* qp = q + (size_t)b * DQ_;
        const float* wq = score_w1 + (size_t)(DS_ + DX_) * H_ + t;
        float a0 = score_b1[t], a1 = 0.f, a2 = 0.f, a3 = 0.f;
        for (int d = 0; d < DQ_; d += 4) {
            const float4 q4 = *(const float4*)(qp + d);      // s_load
            a0 = fmaf(q4.x, wq[(size_t)(d + 0) * H_], a0);
            a1 = fmaf(q4.y, wq[(size_t)(d + 1) * H_], a1);
            a2 = fmaf(q4.z, wq[(size_t)(d + 2) * H_], a2);
            a3 = fmaf(q4.w, wq[(size_t)(d + 3) * H_], a3);
        }
        const float qacc = (a0 + a1) + (a2 + a3);

        float acc[KB];
        #pragma unroll
        for (int kk = 0; kk < KB; ++kk) acc[kk] = qacc;

        const float* xsrc = x0 + ((size_t)b * K_ + kq * KB) * DX_;
        const float* wx   = score_w1 + (size_t)DS_ * H_ + t;
        for (int d = 0; d < DX_; d += 4) {
            const float w0 = wx[(size_t)(d + 0) * H_];
            const float w1 = wx[(size_t)(d + 1) * H_];
            const float w2v = wx[(size_t)(d + 2) * H_];
            const float w3 = wx[(size_t)(d + 3) * H_];
            #pragma unroll
            for (int kk = 0; kk < KB; ++kk) {
                const float4 x4 = *(const float4*)(xsrc + (size_t)kk * DX_ + d);
                acc[kk] = fmaf(x4.x, w0, acc[kk]);
                acc[kk] = fmaf(x4.y, w1, acc[kk]);
                acc[kk] = fmaf(x4.z, w2v, acc[kk]);
                acc[kk] = fmaf(x4.w, w3, acc[kk]);
            }
        }
        #pragma unroll
        for (int kk = 0; kk < KB; ++kk)
            cvec[((size_t)b * K_ + kq * KB + kk) * H_ + t] = acc[kk];
        return;
    }

    const int g    = bid - 128;
    const int tile = g & 127;
    const int mc   = g >> 7;
    const int mat  = mc & 1;
    const int dq   = mc >> 1;
    const int lane = t & 63;
    const int wid  = __builtin_amdgcn_readfirstlane(t >> 6);  // wave id 0..3

    // weights: lane's h-quad, fp32, row stride H_ (=64 float4)
    const float4* wq = (const float4*)((mat ? h_w1 : score_w1)
                                       + (size_t)(dq * DCH) * H_ + 4 * lane);
    // s2: 4 wave-uniform rows -> scalar loads
    const float* srow = s2 + (size_t)(tile * TMA + wid * 4) * DS_ + dq * DCH;

    float4 acc0 = {0,0,0,0}, acc1 = {0,0,0,0}, acc2 = {0,0,0,0}, acc3 = {0,0,0,0};
    float4 c0 = wq[0], c1 = wq[64], c2 = wq[128], c3 = wq[192];

    for (int d4 = 0; d4 < DCH; d4 += 4) {
        const int dn = (d4 + 4 < DCH) ? d4 + 4 : d4;     // clamped prefetch
        const float4 n0 = wq[(size_t)(dn + 0) * 64];
        const float4 n1 = wq[(size_t)(dn + 1) * 64];
        const float4 n2 = wq[(size_t)(dn + 2) * 64];
        const float4 n3 = wq[(size_t)(dn + 3) * 64];

        const float4 s0 = *(const float4*)(srow + 0 * DS_ + d4);  // s_load_dwordx4
        const float4 s1 = *(const float4*)(srow + 1 * DS_ + d4);
        const float4 s2v = *(const float4*)(srow + 2 * DS_ + d4);
        const float4 s3 = *(const float4*)(srow + 3 * DS_ + d4);

        FMA4(acc0, s0.x, c0)  FMA4(acc0, s0.y, c1)  FMA4(acc0, s0.z, c2)  FMA4(acc0, s0.w, c3)
        FMA4(acc1, s1.x, c0)  FMA4(acc1, s1.y, c1)  FMA4(acc1, s1.z, c2)  FMA4(acc1, s1.w, c3)
        FMA4(acc2, s2v.x, c0) FMA4(acc2, s2v.y, c1) FMA4(acc2, s2v.z, c2) FMA4(acc2, s2v.w, c3)
        FMA4(acc3, s3.x, c0)  FMA4(acc3, s3.y, c1)  FMA4(acc3, s3.z, c2)  FMA4(acc3, s3.w, c3)

        c0 = n0; c1 = n1; c2 = n2; c3 = n3;
    }

    float* dst = (mat ? ph1 : pre_s)
               + (size_t)(tile * TMA + wid * 4) * H_ + 4 * lane;
    #pragma unroll
    for (int r = 0; r < 4; ++r) {
        const float4 a = (r == 0) ? acc0 : (r == 1) ? acc1 : (r == 2) ? acc2 : acc3;
        atomicAdd(dst + (size_t)r * H_ + 0, a.x);
        atomicAdd(dst + (size_t)r * H_ + 1, a.y);
        atomicAdd(dst + (size_t)r * H_ + 2, a.z);
        atomicAdd(dst + (size_t)r * H_ + 3, a.w);
    }
}

// ---------------------------------------------------------------------------
// Kernel C: one block per (b,k).
//   logit[m] = sum_h relu(pre_s[b,m,h] + cvec[b,k,h]) * w2[h]
//     (float4 loads; LDS-transpose reduce; wave0 folds + softmax)
//   ragg[h]  = sum_m att[m] * relu(ph1[b,m,h] + h_b1[h])
//   out[b,k,128:256] = ragg . h_w2 + h_b2 ;  out[b,k,0:128] = x0
// ---------------------------------------------------------------------------
__global__ __launch_bounds__(256) void kernC(
    const float* __restrict__ pre_s,     // (2048,256)
    const float* __restrict__ ph1,       // (2048,256)
    const float* __restrict__ cvec,      // (B*K,256)
    const float* __restrict__ score_w2,  // (256,1)
    const float* __restrict__ h_b1,      // (256)
    const float* __restrict__ h_w2,      // (256,128)
    const float* __restrict__ h_b2,      // (128)
    const float* __restrict__ x0,        // (B*K,128)
    float* __restrict__ out)             // (B*K,256)
{
    __shared__ float red[M_][65];        // padded: conflict-free transpose
    __shared__ float att[M_];
    __shared__ float cw[H_];             // ragg
    __shared__ float part[DX_];

    const int t    = threadIdx.x;
    const int bk   = blockIdx.x;         // 0..1151
    const int b    = bk / K_;
    const int wave = t >> 6, lane = t & 63;

    // per-lane h-quad constants (coalesced global reads, L2-hot)
    const float4 cf = *(const float4*)(cvec + (size_t)bk * H_ + 4 * lane);
    const float4 wf = *(const float4*)(score_w2 + 4 * lane);

    // phase 1: red[m][lane] = sum over this lane's 4 h's
    const float* ps = pre_s + (size_t)b * M_ * H_;
    #pragma unroll 4
    for (int mi = 0; mi < M_ / 4; ++mi) {
        const int m = wave * (M_ / 4) + mi;
        const float4 p = *(const float4*)(ps + (size_t)m * H_ + 4 * lane);
        red[m][lane] = fmaxf(p.x + cf.x, 0.f) * wf.x
                     + fmaxf(p.y + cf.y, 0.f) * wf.y
                     + fmaxf(p.z + cf.z, 0.f) * wf.z
                     + fmaxf(p.w + cf.w, 0.f) * wf.w;
    }
    __syncthreads();

    // phase 2 + softmax: wave 0, lane = m
    if (wave == 0) {
        float a0 = 0.f, a1 = 0.f, a2 = 0.f, a3 = 0.f;
        #pragma unroll 4
        for (int l = 0; l < 64; l += 4) {
            a0 += red[lane][l + 0];
            a1 += red[lane][l + 1];
            a2 += red[lane][l + 2];
            a3 += red[lane][l + 3];
        }
        const float L = (a0 + a1) + (a2 + a3);   // logit[m=lane]
        float mx = L;                            // softmax (score_b2 cancels)
        #pragma unroll
        for (int off = 32; off > 0; off >>= 1)
            mx = fmaxf(mx, __shfl_xor(mx, off, 64));
        const float e = expf(L - mx);
        float s = e;
        #pragma unroll
        for (int off = 32; off > 0; off >>= 1)
            s += __shfl_xor(s, off, 64);
        att[lane] = e / s;
    }
    __syncthreads();

    // phase 3: ragg[h=t] = sum_m att[m] * relu(ph1[b,m,t] + h_b1[t])
    {
        const float* hp = ph1 + (size_t)b * M_ * H_ + t;
        const float b1v = h_b1[t];
        float r0 = 0.f, r1 = 0.f;
        #pragma unroll 8
        for (int m = 0; m < M_; m += 2) {
            r0 = fmaf(att[m],     fmaxf(hp[(size_t)m * H_] + b1v, 0.f), r0);
            r1 = fmaf(att[m + 1], fmaxf(hp[(size_t)(m + 1) * H_] + b1v, 0.f), r1);
        }
        cw[t] = r0 + r1;
    }
    __syncthreads();

    // phase 4: out[128:256] = ragg . h_w2 + h_b2, split-K across thread halves
    const int f  = t & 127;
    const int hh = t >> 7;               // wave-uniform (waves 0,1 -> 0; 2,3 -> 1)
    const float* wp = h_w2 + (size_t)(hh * 128) * DX_ + f;
    float a0 = 0.f, a1 = 0.f, a2 = 0.f, a3 = 0.f;
    for (int h = 0; h < 128; h += 4) {
        a0 = fmaf(cw[hh * 128 + h + 0], wp[(size_t)(h + 0) * DX_], a0);
        a1 = fmaf(cw[hh * 128 + h + 1], wp[(size_t)(h + 1) * DX_], a1);
        a2 = fmaf(cw[hh * 128 + h + 2], wp[(size_t)(h + 2) * DX_], a2);
        a3 = fmaf(cw[hh * 128 + h + 3], wp[(size_t)(h + 3) * DX_], a3);
    }
    const float sum = (a0 + a1) + (a2 + a3);
    if (hh) part[f] = sum;
    __syncthreads();

    float* o = out + (size_t)bk * (2 * DX_);
    if (!hh) {
        o[DX_ + f] = sum + part[f] + h_b2[f];
    } else {
        o[f] = x0[(size_t)bk * DX_ + f];   // coalesced passthrough
    }
}

extern "C" void kernel_launch(void* const* d_in, const int* in_sizes, int n_in,
                              void* d_out, int out_size, void* d_ws, size_t ws_size,
                              hipStream_t stream) {
    (void)in_sizes; (void)n_in; (void)out_size; (void)ws_size;
    const float* s2       = (const float*)d_in[0];
    const float* x0       = (const float*)d_in[1];
    const float* q        = (const float*)d_in[2];
    const float* score_w1 = (const float*)d_in[3];
    const float* score_b1 = (const float*)d_in[4];
    const float* score_w2 = (const float*)d_in[5];
    // d_in[6] = score_b2 (cancels in softmax)
    const float* h_w1     = (const float*)d_in[7];
    const float* h_b1     = (const float*)d_in[8];
    const float* h_w2     = (const float*)d_in[9];
    const float* h_b2     = (const float*)d_in[10];
    float* out = (float*)d_out;

    float* ws    = (float*)d_ws;
    float* pre_s = ws;                                 // 2048*256
    float* ph1   = pre_s + (size_t)B_ * M_ * H_;       // 2048*256
    float* cvec  = ph1   + (size_t)B_ * M_ * H_;       // 1152*256

    // zero atomic accumulators: pre_s + ph1 = 4 MB
    hipMemsetAsync(d_ws, 0, (size_t)2 * B_ * M_ * H_ * sizeof(float), stream);

    kernA<<<1152, 256, 0, stream>>>(s2, score_w1, h_w1, q, score_b1, x0,
                                    pre_s, ph1, cvec);
    kernC<<<B_ * K_, 256, 0, stream>>>(pre_s, ph1, cvec, score_w2, h_b1,
                                       h_w2, h_b2, x0, out);
}